// Round 1
// baseline (149.097 us; speedup 1.0000x reference)
//
#include <hip/hip_runtime.h>
#include <math.h>

#define ISZ   64
#define NPIX  4096           // ISZ*ISZ
#define BNB   4
#define NFACE 1024
#define CHUNK 64
#define NCH   16             // NFACE/CHUNK
#define SZ1   (BNB*NCH*NPIX) // per-field chunk-stat count = 262144
#define NEARP 1.0f
#define FARP  100.0f
#define EPSV  0.001f
#define INV_SIGMA 1.0e5f
#define INV_GAMMA 1.0e4f
#define THRESH 9.210240366975849e-5f   // SIGMA*log(1/DIST_EPS - 1)

__device__ __forceinline__ float frcp(float x){ return __builtin_amdgcn_rcpf(x); }
__device__ __forceinline__ float clamp01(float x){ return fminf(fmaxf(x, 0.0f), 1.0f); }

__device__ __forceinline__ float edge_d2f(float px, float py, float ax, float ay,
                                          float bx, float by){
    float ex = bx - ax, ey = by - ay;
    float l2 = ex*ex + ey*ey + 1e-12f;
    float tt = ((px-ax)*ex + (py-ay)*ey) * frcp(l2);
    tt = fminf(fmaxf(tt, 0.0f), 1.0f);
    float dx = px - (ax + tt*ex);
    float dy = py - (ay + tt*ey);
    return dx*dx + dy*dy;
}

struct FaceRes {
    float znm;
    float D;
    float coef;
    float t0, t1, t2;
};

template<bool FULL>
__device__ __forceinline__ FaceRes face_eval(const float* __restrict__ v,
                                             const float* __restrict__ t,
                                             float px, float py)
{
    FaceRes r;
    float x0=v[0], y0=v[1], z0=v[2];
    float x1=v[3], y1=v[4], z1=v[5];
    float x2=v[6], y2=v[7], z2=v[8];

    // barycentric
    float a0 = y1 - y2, a1 = x2 - x1;
    float det = a0*(x0 - x2) + a1*(y0 - y2);
    det = (fabsf(det) < 1e-10f) ? 1e-10f : det;
    float rdet = frcp(det);
    float pxc = px - x2, pyc = py - y2;
    float w0 = (a0*pxc + a1*pyc) * rdet;
    float w1 = ((y2 - y0)*pxc + (x0 - x2)*pyc) * rdet;
    float w2 = 1.0f - w0 - w1;
    bool inside = (w0 > 0.0f) && (w1 > 0.0f) && (w2 > 0.0f);

    // min squared distance to the 3 edges (clamped segment projection)
    float d2 = fminf(fminf(edge_d2f(px,py, x0,y0, x1,y1),
                           edge_d2f(px,py, x1,y1, x2,y2)),
                     edge_d2f(px,py, x2,y2, x0,y0));

    // normalized clipped barycentric -> z interpolation
    float wc0 = clamp01(w0), wc1 = clamp01(w1), wc2 = clamp01(w2);
    float rs = frcp(wc0 + wc1 + wc2 + 1e-12f);
    float wn0 = wc0*rs, wn1 = wc1*rs, wn2 = wc2*rs;
    float invzp = wn0*frcp(z0) + wn1*frcp(z1) + wn2*frcp(z2);
    float zp = frcp(invzp);
    bool valid = (zp > NEARP) && (zp < FARP);
    float zn = (FARP - zp) * (1.0f/(FARP - NEARP));

    // coef > 0  <=>  valid && (inside || d2 < THRESH)
    bool covered = valid && (inside || (d2 < THRESH));
    r.znm = covered ? zn : -1.0f;

    if (FULL) {
        float x = d2 * INV_SIGMA;
        float arg = inside ? -x : x;          // = -sgn*d2/sigma
        float e = __expf(arg);
        float D = frcp(1.0f + e);             // sigmoid(sgn*d2/sigma)
        if (!inside && d2 >= THRESH) D = 0.0f;
        r.D = D;
        r.coef = valid ? D : 0.0f;
        // texture dot per channel: wn0*ft[0][c] + wn1*ft[1][c] + wn2*ft[2][c]
        r.t0 = wn0*t[0] + wn1*t[3] + wn2*t[6];
        r.t1 = wn0*t[1] + wn1*t[4] + wn2*t[7];
        r.t2 = wn0*t[2] + wn1*t[5] + wn2*t[8];
    }
    return r;
}

// K1: one thread per (pixel, face-chunk). Pass A: chunk max of znm.
// Pass B: full eval, write D and chunk-scaled w~, accumulate chunk stats.
__global__ __launch_bounds__(256) void k1_faces(const float* __restrict__ fv,
                                                const float* __restrict__ ft,
                                                float* __restrict__ outD,
                                                float* __restrict__ outW,
                                                float* __restrict__ stats)
{
    __shared__ float sfv[CHUNK*9];
    __shared__ float sft[CHUNK*9];
    const int tid = threadIdx.x;
    const int pix = blockIdx.x*256 + tid;
    const int ch  = blockIdx.y;
    const int b   = blockIdx.z;
    const int fbase = ch*CHUNK;

    const float* gfv = fv + (size_t)(b*NFACE + fbase)*9;
    const float* gft = ft + (size_t)(b*NFACE + fbase)*9;
    for (int e = tid; e < CHUNK*9; e += 256){ sfv[e] = gfv[e]; sft[e] = gft[e]; }
    __syncthreads();

    const int i = pix >> 6, j = pix & 63;
    const float px = (2.0f*(float)j + 1.0f - (float)ISZ) * (1.0f/(float)ISZ);
    const float py = ((float)ISZ - 1.0f - 2.0f*(float)i) * (1.0f/(float)ISZ);

    // pass A: chunk-local max of znm
    float m_c = -1.0f;
    for (int k = 0; k < CHUNK; ++k) {
        FaceRes r = face_eval<false>(&sfv[k*9], &sft[k*9], px, py);
        m_c = fmaxf(m_c, r.znm);
    }

    // pass B: full eval
    float s_c = 0.0f, rgb0 = 0.0f, rgb1 = 0.0f, rgb2 = 0.0f, prod_c = 1.0f;
    const size_t gbase = (size_t)(b*NFACE + fbase)*NPIX + (size_t)pix;
    for (int k = 0; k < CHUNK; ++k) {
        FaceRes r = face_eval<true>(&sfv[k*9], &sft[k*9], px, py);
        float wt = r.coef * __expf((r.znm - m_c) * INV_GAMMA);
        s_c  += wt;
        rgb0 += wt * r.t0;
        rgb1 += wt * r.t1;
        rgb2 += wt * r.t2;
        prod_c *= (1.0f - r.D);
        outD[gbase + (size_t)k*NPIX] = r.D;
        outW[gbase + (size_t)k*NPIX] = wt;
    }

    const int o = (b*NCH + ch)*NPIX + pix;
    stats[o]         = m_c;
    stats[SZ1   + o] = s_c;
    stats[2*SZ1 + o] = rgb0;
    stats[3*SZ1 + o] = rgb1;
    stats[4*SZ1 + o] = rgb2;
    stats[5*SZ1 + o] = prod_c;
}

// K2: per pixel: merge chunk stats, write images, write per-chunk rescale.
__global__ __launch_bounds__(256) void k2_combine(const float* __restrict__ stats,
                                                  float* __restrict__ rfac,
                                                  float* __restrict__ imgs)
{
    const int pix = blockIdx.x*256 + threadIdx.x;
    const int b   = blockIdx.y;

    const float* m_st = stats;
    const float* s_st = stats +   SZ1;
    const float* r0_st = stats + 2*SZ1;
    const float* r1_st = stats + 3*SZ1;
    const float* r2_st = stats + 4*SZ1;
    const float* p_st  = stats + 5*SZ1;

    float m = EPSV;
    #pragma unroll
    for (int c = 0; c < NCH; ++c) {
        m = fmaxf(m, m_st[(b*NCH + c)*NPIX + pix]);
    }

    float denom = __expf((EPSV - m) * INV_GAMMA);   // wbg
    float rgb0 = 0.0f, rgb1 = 0.0f, rgb2 = 0.0f, prodall = 1.0f;
    float ec[NCH];
    #pragma unroll
    for (int c = 0; c < NCH; ++c) {
        const int o = (b*NCH + c)*NPIX + pix;
        float e = __expf((m_st[o] - m) * INV_GAMMA);
        ec[c] = e;
        denom += s_st[o] * e;
        rgb0  += r0_st[o] * e;
        rgb1  += r1_st[o] * e;
        rgb2  += r2_st[o] * e;
        prodall *= p_st[o];
    }
    float invd = frcp(denom);
    #pragma unroll
    for (int c = 0; c < NCH; ++c) {
        rfac[(b*NCH + c)*NPIX + pix] = ec[c] * invd;
    }
    imgs[(size_t)(b*4 + 0)*NPIX + pix] = rgb0 * invd;   // BG = 0
    imgs[(size_t)(b*4 + 1)*NPIX + pix] = rgb1 * invd;
    imgs[(size_t)(b*4 + 2)*NPIX + pix] = rgb2 * invd;
    imgs[(size_t)(b*4 + 3)*NPIX + pix] = 1.0f - prodall;
}

// K3: aggr (holds chunk-scaled w~) *= per-(pixel,chunk) rescale factor.
__global__ __launch_bounds__(256) void k3_scale(float* __restrict__ aggr,
                                                const float* __restrict__ rfac)
{
    const int idx = blockIdx.x*256 + threadIdx.x;  // < BNB*NFACE*NPIX
    const int pix = idx & (NPIX - 1);
    const int bf  = idx >> 12;
    const int f   = bf & (NFACE - 1);
    const int b   = bf >> 10;
    const int c   = f >> 6;                         // CHUNK = 64
    aggr[idx] = aggr[idx] * rfac[(b*NCH + c)*NPIX + pix];
}

extern "C" void kernel_launch(void* const* d_in, const int* in_sizes, int n_in,
                              void* d_out, int out_size, void* d_ws, size_t ws_size,
                              hipStream_t stream) {
    const float* fv = (const float*)d_in[0];   // (4,1024,3,3)
    const float* ft = (const float*)d_in[1];   // (4,1024,3,3)
    float* out  = (float*)d_out;
    float* imgs = out;                                  // (4,4,64,64)
    float* outD = out + (size_t)BNB*4*NPIX;             // (4,1024,64,64)
    float* outA = outD + (size_t)BNB*NFACE*NPIX;        // (4,1024,64,64)

    float* ws    = (float*)d_ws;
    float* stats = ws;             // 6*SZ1 floats
    float* rfac  = ws + 6*SZ1;     // SZ1 floats    (total ~7.3 MB)

    dim3 g1(NPIX/256, NCH, BNB);
    k1_faces<<<g1, dim3(256), 0, stream>>>(fv, ft, outD, outA, stats);

    dim3 g2(NPIX/256, BNB);
    k2_combine<<<g2, dim3(256), 0, stream>>>(stats, rfac, imgs);

    const int total = BNB*NFACE*NPIX;
    k3_scale<<<total/256, dim3(256), 0, stream>>>(outA, rfac);
}

// Round 2
// 112.590 us; speedup vs baseline: 1.3242x; 1.3242x over previous
//
#include <hip/hip_runtime.h>
#include <math.h>

#define ISZ   64
#define NPIX  4096           // ISZ*ISZ
#define BNB   4
#define NFACE 1024
#define CHUNK 64
#define NCH   16             // NFACE/CHUNK
#define SZ1   (BNB*NCH*NPIX) // per-field chunk-stat count = 262144
#define NEARP 1.0f
#define FARP  100.0f
#define EPSV  0.001f
#define INV_SIGMA 1.0e5f
#define INV_GAMMA 1.0e4f
#define THRESH 9.210240366975849e-5f   // SIGMA*log(1/DIST_EPS - 1)
#define NQ 11                // float4 quads per face of precomputed constants

__device__ __forceinline__ float frcp(float x){ return __builtin_amdgcn_rcpf(x); }
__device__ __forceinline__ float clamp01(float x){ return fminf(fmaxf(x, 0.0f), 1.0f); }

// K0: per-face constant precompute.
// Layout per face (11 float4):
//  0: A  = (W0x, W0y, W0c, rz0)      w0 = W0x*px + W0y*py + W0c
//  1: B  = (W1x, W1y, W1c, rz1)
//  2: E0 = (T0x, T0y, T0c, rz2)      t_e = Tx*px + Ty*py + Tc
//  3: F0 = (ax0, ay0, ex0, ey0)
//  4: E1 = (T1x, T1y, T1c, 0)
//  5: F1 = (ax1, ay1, ex1, ey1)
//  6: E2 = (T2x, T2y, T2c, 0)
//  7: F2 = (ax2, ay2, ex2, ey2)
//  8: X0 = (T00, T10, T20, 0)        channel-0 texture at the 3 verts
//  9: X1 = (T01, T11, T21, 0)
// 10: X2 = (T02, T12, T22, 0)
__global__ __launch_bounds__(256) void k0_pre(const float* __restrict__ fv,
                                              const float* __restrict__ ft,
                                              float4* __restrict__ fc)
{
    const int f = blockIdx.x*256 + threadIdx.x;
    if (f >= BNB*NFACE) return;
    const float* v = fv + (size_t)f*9;
    const float* t = ft + (size_t)f*9;
    float x0=v[0],y0=v[1],z0=v[2],x1=v[3],y1=v[4],z1=v[5],x2=v[6],y2=v[7],z2=v[8];

    float a0 = y1 - y2, a1 = x2 - x1;
    float det = a0*(x0 - x2) + a1*(y0 - y2);
    det = (fabsf(det) < 1e-10f) ? 1e-10f : det;
    float rdet = 1.0f/det;
    float b0 = y2 - y0, b1 = x0 - x2;

    float4* o = fc + (size_t)f*NQ;
    o[0] = make_float4(a0*rdet, a1*rdet, -(a0*x2 + a1*y2)*rdet, 1.0f/z0);
    o[1] = make_float4(b0*rdet, b1*rdet, -(b0*x2 + b1*y2)*rdet, 1.0f/z1);

    float rz2 = 1.0f/z2;
    const float axs[3] = {x0, x1, x2}, ays[3] = {y0, y1, y2};
    const float bxs[3] = {x1, x2, x0}, bys[3] = {y1, y2, y0};
    #pragma unroll
    for (int e = 0; e < 3; ++e) {
        float ex = bxs[e] - axs[e], ey = bys[e] - ays[e];
        float inv = 1.0f/(ex*ex + ey*ey + 1e-12f);
        o[2 + 2*e] = make_float4(ex*inv, ey*inv, -(axs[e]*ex + ays[e]*ey)*inv,
                                 (e == 0) ? rz2 : 0.0f);
        o[3 + 2*e] = make_float4(axs[e], ays[e], ex, ey);
    }
    o[8]  = make_float4(t[0], t[3], t[6], 0.0f);
    o[9]  = make_float4(t[1], t[4], t[7], 0.0f);
    o[10] = make_float4(t[2], t[5], t[8], 0.0f);
}

__device__ __forceinline__ float edge_d2q(float px, float py, float4 E, float4 F){
    float tt = clamp01(E.x*px + E.y*py + E.z);
    float dx = px - F.x - tt*F.z;
    float dy = py - F.y - tt*F.w;
    return dx*dx + dy*dy;
}

// K1: one thread per (pixel, face-chunk). Pass A: chunk max of znm.
// Pass B: full eval, write D and chunk-scaled w~, accumulate chunk stats.
__global__ __launch_bounds__(256) void k1_faces(const float4* __restrict__ fc,
                                                float* __restrict__ outD,
                                                float* __restrict__ outW,
                                                float* __restrict__ stats)
{
    __shared__ float4 sfc[CHUNK*NQ];   // 11264 B
    const int tid = threadIdx.x;
    const int pix = blockIdx.x*256 + tid;
    const int ch  = blockIdx.y;
    const int b   = blockIdx.z;
    const int fbase = ch*CHUNK;

    const float4* g = fc + (size_t)(b*NFACE + fbase)*NQ;
    for (int e = tid; e < CHUNK*NQ; e += 256) sfc[e] = g[e];
    __syncthreads();

    const int i = pix >> 6, j = pix & 63;
    const float px = (2.0f*(float)j + 1.0f - (float)ISZ) * (1.0f/(float)ISZ);
    const float py = ((float)ISZ - 1.0f - 2.0f*(float)i) * (1.0f/(float)ISZ);

    // pass A: chunk-local max of znm
    float m_c = -1.0f;
    for (int k = 0; k < CHUNK; ++k) {
        const float4* c = &sfc[k*NQ];
        float4 A = c[0], Bq = c[1], E0 = c[2], F0 = c[3];
        float4 E1 = c[4], F1 = c[5], E2 = c[6], F2 = c[7];
        float w0 = A.x*px + A.y*py + A.z;
        float w1 = Bq.x*px + Bq.y*py + Bq.z;
        float w2 = 1.0f - w0 - w1;
        bool inside = (w0 > 0.0f) && (w1 > 0.0f) && (w2 > 0.0f);
        float d2 = fminf(fminf(edge_d2q(px,py,E0,F0), edge_d2q(px,py,E1,F1)),
                         edge_d2q(px,py,E2,F2));
        float wc0 = clamp01(w0), wc1 = clamp01(w1), wc2 = clamp01(w2);
        float s = wc0 + wc1 + wc2 + 1e-12f;
        float tz = wc0*A.w + wc1*Bq.w + wc2*E0.w;
        float zp = s * frcp(tz);
        bool valid = (zp > NEARP) && (zp < FARP);
        float zn = (FARP - zp) * (1.0f/(FARP - NEARP));
        bool covered = valid && (inside || (d2 < THRESH));
        m_c = fmaxf(m_c, covered ? zn : -1.0f);
    }

    // pass B: full eval
    float s_c = 0.0f, rgb0 = 0.0f, rgb1 = 0.0f, rgb2 = 0.0f, prod_c = 1.0f;
    const size_t gbase = (size_t)(b*NFACE + fbase)*NPIX + (size_t)pix;
    for (int k = 0; k < CHUNK; ++k) {
        const float4* c = &sfc[k*NQ];
        float4 A = c[0], Bq = c[1], E0 = c[2], F0 = c[3];
        float4 E1 = c[4], F1 = c[5], E2 = c[6], F2 = c[7];
        float4 X0 = c[8], X1 = c[9], X2 = c[10];
        float w0 = A.x*px + A.y*py + A.z;
        float w1 = Bq.x*px + Bq.y*py + Bq.z;
        float w2 = 1.0f - w0 - w1;
        bool inside = (w0 > 0.0f) && (w1 > 0.0f) && (w2 > 0.0f);
        float d2 = fminf(fminf(edge_d2q(px,py,E0,F0), edge_d2q(px,py,E1,F1)),
                         edge_d2q(px,py,E2,F2));
        float wc0 = clamp01(w0), wc1 = clamp01(w1), wc2 = clamp01(w2);
        float s = wc0 + wc1 + wc2 + 1e-12f;
        float tz = wc0*A.w + wc1*Bq.w + wc2*E0.w;
        float zp = s * frcp(tz);
        bool valid = (zp > NEARP) && (zp < FARP);
        float zn = (FARP - zp) * (1.0f/(FARP - NEARP));
        bool covered = valid && (inside || (d2 < THRESH));
        float znm = covered ? zn : -1.0f;

        float x = d2 * INV_SIGMA;
        float e = __expf(inside ? -x : x);
        float D = frcp(1.0f + e);
        if (!inside && d2 >= THRESH) D = 0.0f;
        float coef = valid ? D : 0.0f;

        float wt = coef * __expf((znm - m_c) * INV_GAMMA);
        float wrs = wt * frcp(s);
        s_c  += wt;
        rgb0 += wrs * (wc0*X0.x + wc1*X0.y + wc2*X0.z);
        rgb1 += wrs * (wc0*X1.x + wc1*X1.y + wc2*X1.z);
        rgb2 += wrs * (wc0*X2.x + wc1*X2.y + wc2*X2.z);
        prod_c *= (1.0f - D);
        outD[gbase + (size_t)k*NPIX] = D;
        outW[gbase + (size_t)k*NPIX] = wt;
    }

    const int o = (b*NCH + ch)*NPIX + pix;
    stats[o]         = m_c;
    stats[SZ1   + o] = s_c;
    stats[2*SZ1 + o] = rgb0;
    stats[3*SZ1 + o] = rgb1;
    stats[4*SZ1 + o] = rgb2;
    stats[5*SZ1 + o] = prod_c;
}

// K2: per pixel: merge chunk stats, write images, write per-chunk rescale.
__global__ __launch_bounds__(256) void k2_combine(const float* __restrict__ stats,
                                                  float* __restrict__ rfac,
                                                  float* __restrict__ imgs)
{
    const int pix = blockIdx.x*256 + threadIdx.x;
    const int b   = blockIdx.y;

    const float* m_st = stats;
    const float* s_st = stats +   SZ1;
    const float* r0_st = stats + 2*SZ1;
    const float* r1_st = stats + 3*SZ1;
    const float* r2_st = stats + 4*SZ1;
    const float* p_st  = stats + 5*SZ1;

    float m = EPSV;
    #pragma unroll
    for (int c = 0; c < NCH; ++c) {
        m = fmaxf(m, m_st[(b*NCH + c)*NPIX + pix]);
    }

    float denom = __expf((EPSV - m) * INV_GAMMA);   // wbg
    float rgb0 = 0.0f, rgb1 = 0.0f, rgb2 = 0.0f, prodall = 1.0f;
    float ec[NCH];
    #pragma unroll
    for (int c = 0; c < NCH; ++c) {
        const int o = (b*NCH + c)*NPIX + pix;
        float e = __expf((m_st[o] - m) * INV_GAMMA);
        ec[c] = e;
        denom += s_st[o] * e;
        rgb0  += r0_st[o] * e;
        rgb1  += r1_st[o] * e;
        rgb2  += r2_st[o] * e;
        prodall *= p_st[o];
    }
    float invd = frcp(denom);
    #pragma unroll
    for (int c = 0; c < NCH; ++c) {
        rfac[(b*NCH + c)*NPIX + pix] = ec[c] * invd;
    }
    imgs[(size_t)(b*4 + 0)*NPIX + pix] = rgb0 * invd;   // BG = 0
    imgs[(size_t)(b*4 + 1)*NPIX + pix] = rgb1 * invd;
    imgs[(size_t)(b*4 + 2)*NPIX + pix] = rgb2 * invd;
    imgs[(size_t)(b*4 + 3)*NPIX + pix] = 1.0f - prodall;
}

// K3: aggr (holds chunk-scaled w~) *= per-(pixel,chunk) rescale factor.
__global__ __launch_bounds__(256) void k3_scale(float* __restrict__ aggr,
                                                const float* __restrict__ rfac)
{
    const int idx = blockIdx.x*256 + threadIdx.x;  // < BNB*NFACE*NPIX
    const int pix = idx & (NPIX - 1);
    const int bf  = idx >> 12;
    const int f   = bf & (NFACE - 1);
    const int b   = bf >> 10;
    const int c   = f >> 6;                         // CHUNK = 64
    aggr[idx] = aggr[idx] * rfac[(b*NCH + c)*NPIX + pix];
}

extern "C" void kernel_launch(void* const* d_in, const int* in_sizes, int n_in,
                              void* d_out, int out_size, void* d_ws, size_t ws_size,
                              hipStream_t stream) {
    const float* fv = (const float*)d_in[0];   // (4,1024,3,3)
    const float* ft = (const float*)d_in[1];   // (4,1024,3,3)
    float* out  = (float*)d_out;
    float* imgs = out;                                  // (4,4,64,64)
    float* outD = out + (size_t)BNB*4*NPIX;             // (4,1024,64,64)
    float* outA = outD + (size_t)BNB*NFACE*NPIX;        // (4,1024,64,64)

    float* ws    = (float*)d_ws;
    float4* fcns = (float4*)ws;                  // BNB*NFACE*NQ float4 = 0.72 MB
    float* stats = ws + (size_t)BNB*NFACE*NQ*4;  // 6*SZ1 floats
    float* rfac  = stats + 6*SZ1;                // SZ1 floats   (total ~8.1 MB)

    k0_pre<<<(BNB*NFACE + 255)/256, dim3(256), 0, stream>>>(fv, ft, fcns);

    dim3 g1(NPIX/256, NCH, BNB);
    k1_faces<<<g1, dim3(256), 0, stream>>>(fcns, outD, outA, stats);

    dim3 g2(NPIX/256, BNB);
    k2_combine<<<g2, dim3(256), 0, stream>>>(stats, rfac, imgs);

    const int total = BNB*NFACE*NPIX;
    k3_scale<<<total/256, dim3(256), 0, stream>>>(outA, rfac);
}

// Round 3
// 100.341 us; speedup vs baseline: 1.4859x; 1.1221x over previous
//
#include <hip/hip_runtime.h>
#include <math.h>

#define ISZ   64
#define NPIX  4096
#define BNB   4
#define NFACE 1024
#define NTILE 16            // 4x4 tiles of 16x16 px
#define CHB   64            // faces per compute chunk
#define MAXCH 16            // NFACE/CHB
#define STS   (BNB*NTILE*MAXCH*256)   // 262144 per stats field
#define NEARP 1.0f
#define FARP  100.0f
#define EPSV  0.001f
#define INV_SIGMA 1.0e5f
#define INV_GAMMA 1.0e4f
#define THRESH 9.210240366975849e-5f  // SIGMA*log(1/DIST_EPS - 1)
#define RDIL  0.0105f                 // > sqrt(THRESH)=0.009597, 20% fp margin
#define NQ    12                      // 11 const quads + 1 bbox int4

__device__ __forceinline__ float frcp(float x){ return __builtin_amdgcn_rcpf(x); }
__device__ __forceinline__ float clamp01(float x){ return fminf(fmaxf(x, 0.0f), 1.0f); }

__device__ __forceinline__ float edge_d2q(float px, float py, float4 E, float4 F){
    float tt = clamp01(E.x*px + E.y*py + E.z);
    float dx = px - F.x - tt*F.z;
    float dy = py - F.y - tt*F.w;
    return dx*dx + dy*dy;
}

// K0: per-face constants (quads 0..10 as in R2) + quad 11 = int4 bbox
// (row_lo, row_hi, quadcol_lo, quadcol_hi), dilated by RDIL.
__global__ __launch_bounds__(256) void k0_pre(const float* __restrict__ fv,
                                              const float* __restrict__ ft,
                                              float4* __restrict__ fc)
{
    const int f = blockIdx.x*256 + threadIdx.x;
    if (f >= BNB*NFACE) return;
    const float* v = fv + (size_t)f*9;
    const float* t = ft + (size_t)f*9;
    float x0=v[0],y0=v[1],z0=v[2],x1=v[3],y1=v[4],z1=v[5],x2=v[6],y2=v[7],z2=v[8];

    float a0 = y1 - y2, a1 = x2 - x1;
    float det = a0*(x0 - x2) + a1*(y0 - y2);
    det = (fabsf(det) < 1e-10f) ? 1e-10f : det;
    float rdet = 1.0f/det;
    float b0 = y2 - y0, b1 = x0 - x2;

    float4* o = fc + (size_t)f*NQ;
    o[0] = make_float4(a0*rdet, a1*rdet, -(a0*x2 + a1*y2)*rdet, 1.0f/z0);
    o[1] = make_float4(b0*rdet, b1*rdet, -(b0*x2 + b1*y2)*rdet, 1.0f/z1);

    float rz2 = 1.0f/z2;
    const float axs[3] = {x0, x1, x2}, ays[3] = {y0, y1, y2};
    const float bxs[3] = {x1, x2, x0}, bys[3] = {y1, y2, y0};
    #pragma unroll
    for (int e = 0; e < 3; ++e) {
        float ex = bxs[e] - axs[e], ey = bys[e] - ays[e];
        float inv = 1.0f/(ex*ex + ey*ey + 1e-12f);
        o[2 + 2*e] = make_float4(ex*inv, ey*inv, -(axs[e]*ex + ays[e]*ey)*inv,
                                 (e == 0) ? rz2 : 0.0f);
        o[3 + 2*e] = make_float4(axs[e], ays[e], ex, ey);
    }
    o[8]  = make_float4(t[0], t[3], t[6], 0.0f);
    o[9]  = make_float4(t[1], t[4], t[7], 0.0f);
    o[10] = make_float4(t[2], t[5], t[8], 0.0f);

    float xmn = fminf(fminf(x0,x1),x2) - RDIL, xmx = fmaxf(fmaxf(x0,x1),x2) + RDIL;
    float ymn = fminf(fminf(y0,y1),y2) - RDIL, ymx = fmaxf(fmaxf(y0,y1),y2) + RDIL;
    // px(j) = (2j+1-64)/64 -> j in [32*xmn+31.5, 32*xmx+31.5]
    // py(i) = (63-2i)/64   -> i in [31.5-32*ymx, 31.5-32*ymn]
    int jl = (int)ceilf (32.0f*xmn + 31.5f);
    int jh = (int)floorf(32.0f*xmx + 31.5f);
    int il = (int)ceilf (31.5f - 32.0f*ymx);
    int ih = (int)floorf(31.5f - 32.0f*ymn);
    jl = max(jl, 0); jh = min(jh, 63); il = max(il, 0); ih = min(ih, 63);
    int4 bb; bb.x = il; bb.y = ih; bb.z = jl >> 2; bb.w = jh >> 2;
    ((int4*)(o + 11))[0] = bb;
}

// K_bin: one wave per (tile,b) builds ordered face list (ballot compaction).
__global__ __launch_bounds__(64) void k_bin(const float4* __restrict__ fc,
                                            int* __restrict__ lists,
                                            int* __restrict__ lens)
{
    const int t = blockIdx.x, b = blockIdx.y, lane = threadIdx.x;
    const int ty0 = (t>>2)*16, ty1 = ty0+15;
    const int tx0 = (t&3)*16,  tx1 = tx0+15;
    int* lst = lists + (b*NTILE + t)*NFACE;
    int base = 0;
    for (int r = 0; r < NFACE/64; ++r) {
        int f = r*64 + lane;
        int4 bb = ((const int4*)fc)[(size_t)(b*NFACE+f)*NQ + 11];
        bool hit = (bb.y >= ty0) && (bb.x <= ty1) &&
                   (bb.w*4 + 3 >= tx0) && (bb.z*4 <= tx1);
        unsigned long long m = __ballot(hit);
        if (hit) {
            int pos = __popcll(m & ((1ull << lane) - 1ull));
            lst[base + pos] = f;
        }
        base += __popcll(m);
    }
    if (lane == 0) lens[b*NTILE + t] = base;
}

// K_main: blocks [0, BNB*NTILE*MAXCH) = compute role (binned eval, writes bbox
// quads + chunk stats). Remaining blocks = fill role (zero-fill all quads
// NOT in the owning face's bbox). Address sets are exact complements.
__global__ __launch_bounds__(256) void k_main(const float4* __restrict__ fc,
                                              const int* __restrict__ lists,
                                              const int* __restrict__ lens,
                                              float* __restrict__ outD,
                                              float* __restrict__ outW,
                                              float* __restrict__ stats)
{
    __shared__ float4 sfc[CHB*NQ];
    __shared__ int sfid[CHB];
    const int bid = blockIdx.x;
    const int tid = threadIdx.x;

    if (bid >= BNB*NTILE*MAXCH) {
        // ---- fill role: one float4 quad per thread, both arrays ----
        int qid = (bid - BNB*NTILE*MAXCH)*256 + tid;      // < 4*2^20
        int b = qid >> 20;
        int f = (qid >> 10) & (NFACE-1);
        int i = (qid >> 4) & 63;
        int q = qid & 15;
        int4 bb = ((const int4*)fc)[(size_t)(b*NFACE+f)*NQ + 11];
        bool hole = (i >= bb.x) && (i <= bb.y) && (q >= bb.z) && (q <= bb.w);
        if (!hole) {
            size_t off = (size_t)(b*NFACE + f)*NPIX + i*64 + q*4;
            float4 z = make_float4(0.f, 0.f, 0.f, 0.f);
            *(float4*)(outD + off) = z;
            *(float4*)(outW + off) = z;
        }
        return;
    }

    // ---- compute role ----
    const int c = bid & (MAXCH-1);
    const int t = (bid >> 4) & (NTILE-1);
    const int b = bid >> 8;
    const int len = lens[b*NTILE + t];
    const int nst = c*CHB;
    if (nst >= len) return;
    const int n = min(CHB, len - nst);
    const int* lst = lists + (b*NTILE + t)*NFACE + nst;

    for (int e = tid; e < n*NQ; e += 256) {
        int k = (int)((unsigned)e / (unsigned)NQ);
        int qd = e - k*NQ;
        sfc[k*NQ + qd] = fc[((size_t)b*NFACE + lst[k])*NQ + qd];
    }
    if (tid < n) sfid[tid] = lst[tid];
    __syncthreads();

    const int rr = tid >> 4, cc = tid & 15;
    const int i = (t>>2)*16 + rr;
    const int j = (t&3)*16 + cc;
    const int jq = j >> 2;
    const float px = (2.0f*(float)j + 1.0f - (float)ISZ) * (1.0f/(float)ISZ);
    const float py = ((float)ISZ - 1.0f - 2.0f*(float)i) * (1.0f/(float)ISZ);

    // pass A: chunk max of znm (skipped faces contribute exactly -1)
    float m_c = -1.0f;
    for (int k = 0; k < n; ++k) {
        const float4* cf = &sfc[k*NQ];
        int4 bb = ((const int4*)cf)[11];
        bool act = (i >= bb.x) && (i <= bb.y) && (jq >= bb.z) && (jq <= bb.w);
        if (act) {
            float4 A = cf[0], Bq = cf[1], E0 = cf[2], F0 = cf[3];
            float4 E1 = cf[4], F1 = cf[5], E2 = cf[6], F2 = cf[7];
            float w0 = A.x*px + A.y*py + A.z;
            float w1 = Bq.x*px + Bq.y*py + Bq.z;
            float w2 = 1.0f - w0 - w1;
            bool inside = (w0 > 0.0f) && (w1 > 0.0f) && (w2 > 0.0f);
            float d2 = fminf(fminf(edge_d2q(px,py,E0,F0), edge_d2q(px,py,E1,F1)),
                             edge_d2q(px,py,E2,F2));
            float wc0 = clamp01(w0), wc1 = clamp01(w1), wc2 = clamp01(w2);
            float s = wc0 + wc1 + wc2 + 1e-12f;
            float tz = wc0*A.w + wc1*Bq.w + wc2*E0.w;
            float zp = s * frcp(tz);
            bool valid = (zp > NEARP) && (zp < FARP);
            float zn = (FARP - zp) * (1.0f/(FARP - NEARP));
            bool covered = valid && (inside || (d2 < THRESH));
            m_c = fmaxf(m_c, covered ? zn : -1.0f);
        }
    }

    // pass B: full eval + sparse writes + chunk stats
    float s_c = 0.0f, rgb0 = 0.0f, rgb1 = 0.0f, rgb2 = 0.0f, prod_c = 1.0f;
    for (int k = 0; k < n; ++k) {
        const float4* cf = &sfc[k*NQ];
        int4 bb = ((const int4*)cf)[11];
        bool act = (i >= bb.x) && (i <= bb.y) && (jq >= bb.z) && (jq <= bb.w);
        if (act) {
            float4 A = cf[0], Bq = cf[1], E0 = cf[2], F0 = cf[3];
            float4 E1 = cf[4], F1 = cf[5], E2 = cf[6], F2 = cf[7];
            float4 X0 = cf[8], X1 = cf[9], X2 = cf[10];
            float w0 = A.x*px + A.y*py + A.z;
            float w1 = Bq.x*px + Bq.y*py + Bq.z;
            float w2 = 1.0f - w0 - w1;
            bool inside = (w0 > 0.0f) && (w1 > 0.0f) && (w2 > 0.0f);
            float d2 = fminf(fminf(edge_d2q(px,py,E0,F0), edge_d2q(px,py,E1,F1)),
                             edge_d2q(px,py,E2,F2));
            float wc0 = clamp01(w0), wc1 = clamp01(w1), wc2 = clamp01(w2);
            float s = wc0 + wc1 + wc2 + 1e-12f;
            float tz = wc0*A.w + wc1*Bq.w + wc2*E0.w;
            float zp = s * frcp(tz);
            bool valid = (zp > NEARP) && (zp < FARP);
            float zn = (FARP - zp) * (1.0f/(FARP - NEARP));
            bool covered = valid && (inside || (d2 < THRESH));
            float znm = covered ? zn : -1.0f;

            float x = d2 * INV_SIGMA;
            float e = __expf(inside ? -x : x);
            float D = frcp(1.0f + e);
            if (!inside && d2 >= THRESH) D = 0.0f;
            float coef = valid ? D : 0.0f;

            float wt = coef * __expf((znm - m_c) * INV_GAMMA);
            float wrs = wt * frcp(s);
            s_c  += wt;
            rgb0 += wrs * (wc0*X0.x + wc1*X0.y + wc2*X0.z);
            rgb1 += wrs * (wc0*X1.x + wc1*X1.y + wc2*X1.z);
            rgb2 += wrs * (wc0*X2.x + wc1*X2.y + wc2*X2.z);
            prod_c *= (1.0f - D);
            size_t off = (size_t)(b*NFACE + sfid[k])*NPIX + i*64 + j;
            outD[off] = D;
            outW[off] = wt;
        }
    }

    const int o = ((b*NTILE + t)*MAXCH + c)*256 + tid;
    stats[o]         = m_c;
    stats[STS   + o] = s_c;
    stats[2*STS + o] = rgb0;
    stats[3*STS + o] = rgb1;
    stats[4*STS + o] = rgb2;
    stats[5*STS + o] = prod_c;
}

// K2: per-pixel merge of the tile's chunk stats -> images + rescale factors.
__global__ __launch_bounds__(256) void k2_combine(const float* __restrict__ stats,
                                                  const int* __restrict__ lens,
                                                  float* __restrict__ rfac,
                                                  float* __restrict__ imgs)
{
    const int t = blockIdx.x, b = blockIdx.y, p = threadIdx.x;
    const int len = lens[b*NTILE + t];
    const int nch = (len + CHB - 1) / CHB;
    const int ob = (b*NTILE + t)*MAXCH*256 + p;

    float m = EPSV;
    for (int c = 0; c < nch; ++c) m = fmaxf(m, stats[ob + c*256]);

    float denom = __expf((EPSV - m) * INV_GAMMA);   // wbg
    float r0 = 0.f, r1 = 0.f, r2 = 0.f, pr = 1.f;
    for (int c = 0; c < nch; ++c) {
        const int o = ob + c*256;
        float e = __expf((stats[o] - m) * INV_GAMMA);
        denom += stats[STS + o]  * e;
        r0    += stats[2*STS + o]* e;
        r1    += stats[3*STS + o]* e;
        r2    += stats[4*STS + o]* e;
        pr    *= stats[5*STS + o];
    }
    float invd = frcp(denom);
    for (int c = 0; c < nch; ++c) {
        rfac[ob + c*256] = __expf((stats[ob + c*256] - m) * INV_GAMMA) * invd;
    }
    const int rr = p >> 4, cc = p & 15;
    const int i = (t>>2)*16 + rr, j = (t&3)*16 + cc;
    size_t ip = (size_t)b*4*NPIX + (size_t)i*64 + j;
    imgs[ip]          = r0 * invd;     // BG = 0
    imgs[ip +   NPIX] = r1 * invd;
    imgs[ip + 2*NPIX] = r2 * invd;
    imgs[ip + 3*NPIX] = 1.0f - pr;
}

// K3: sparse rescale of aggr (only listed faces' bbox quads).
__global__ __launch_bounds__(256) void k3_scale(const float4* __restrict__ fc,
                                                const int* __restrict__ lists,
                                                const int* __restrict__ lens,
                                                const float* __restrict__ rfac,
                                                float* __restrict__ outW)
{
    const int bid = blockIdx.x;
    const int c = bid & (MAXCH-1);
    const int t = (bid >> 4) & (NTILE-1);
    const int b = bid >> 8;
    const int len = lens[b*NTILE + t];
    const int nst = c*CHB;
    if (nst >= len) return;
    const int n = min(CHB, len - nst);
    const int* lst = lists + (b*NTILE + t)*NFACE + nst;
    const int tid = threadIdx.x;
    const int rr = tid >> 4, cc = tid & 15;
    const int i = (t>>2)*16 + rr;
    const int j = (t&3)*16 + cc;
    const int jq = j >> 2;
    const float r = rfac[((b*NTILE + t)*MAXCH + c)*256 + tid];
    for (int k = 0; k < n; ++k) {
        int f = lst[k];
        int4 bb = ((const int4*)fc)[(size_t)(b*NFACE+f)*NQ + 11];
        bool act = (i >= bb.x) && (i <= bb.y) && (jq >= bb.z) && (jq <= bb.w);
        if (act) {
            size_t off = (size_t)(b*NFACE + f)*NPIX + i*64 + j;
            outW[off] *= r;
        }
    }
}

extern "C" void kernel_launch(void* const* d_in, const int* in_sizes, int n_in,
                              void* d_out, int out_size, void* d_ws, size_t ws_size,
                              hipStream_t stream) {
    const float* fv = (const float*)d_in[0];
    const float* ft = (const float*)d_in[1];
    float* out  = (float*)d_out;
    float* imgs = out;
    float* outD = out + (size_t)BNB*4*NPIX;
    float* outA = outD + (size_t)BNB*NFACE*NPIX;

    float* ws    = (float*)d_ws;
    float4* fcq  = (float4*)ws;                         // 4096*12 quads = 768 KB
    int*   lists = (int*)(ws + (size_t)BNB*NFACE*NQ*4); // 4*16*1024 ints = 256 KB
    int*   lens  = lists + BNB*NTILE*NFACE;             // 64 ints
    float* stats = (float*)(lens + BNB*NTILE);          // 6*STS floats = 6 MB
    float* rfac  = stats + 6*STS;                       // STS floats = 1 MB

    k0_pre<<<(BNB*NFACE + 255)/256, 256, 0, stream>>>(fv, ft, fcq);
    k_bin<<<dim3(NTILE, BNB), 64, 0, stream>>>(fcq, lists, lens);

    const int nComp = BNB*NTILE*MAXCH;                  // 1024
    const int nFill = (BNB*NFACE*NPIX/4)/256;           // 16384
    k_main<<<nComp + nFill, 256, 0, stream>>>(fcq, lists, lens, outD, outA, stats);

    k2_combine<<<dim3(NTILE, BNB), 256, 0, stream>>>(stats, lens, rfac, imgs);
    k3_scale<<<BNB*NTILE*MAXCH, 256, 0, stream>>>(fcq, lists, lens, rfac, outA);
}

// Round 4
// 94.651 us; speedup vs baseline: 1.5752x; 1.0601x over previous
//
#include <hip/hip_runtime.h>
#include <math.h>

#define ISZ   64
#define NPIX  4096
#define BNB   4
#define NFACE 1024
#define NTILE 16            // 4x4 tiles of 16x16 px
#define CHB   64            // faces staged per LDS chunk in kA
#define NEARP 1.0f
#define FARP  100.0f
#define EPSV  0.001f
#define INV_SIGMA 1.0e5f
#define INV_GAMMA 1.0e4f
#define THRESH 9.210240366975849e-5f  // SIGMA*log(1/DIST_EPS - 1)
#define RDIL  0.0105f                 // > sqrt(THRESH)=0.009597, fp margin
#define NQ    12                      // 11 const quads + 1 bbox int4

__device__ __forceinline__ float frcp(float x){ return __builtin_amdgcn_rcpf(x); }
__device__ __forceinline__ float clamp01(float x){ return fminf(fmaxf(x, 0.0f), 1.0f); }

__device__ __forceinline__ float edge_d2q(float px, float py, float4 E, float4 F){
    float tt = clamp01(E.x*px + E.y*py + E.z);
    float dx = px - F.x - tt*F.z;
    float dy = py - F.y - tt*F.w;
    return dx*dx + dy*dy;
}

// Evaluate one (face,pixel). Returns D; writes znm, wt-precursor pieces.
struct Ev { float znm, D, coef, s, wc0, wc1, wc2; };
__device__ __forceinline__ Ev face_pixel(const float4* __restrict__ cf,
                                         float px, float py)
{
    Ev r;
    float4 A = cf[0], Bq = cf[1], E0 = cf[2], F0 = cf[3];
    float4 E1 = cf[4], F1 = cf[5], E2 = cf[6], F2 = cf[7];
    float w0 = A.x*px + A.y*py + A.z;
    float w1 = Bq.x*px + Bq.y*py + Bq.z;
    float w2 = 1.0f - w0 - w1;
    bool inside = (w0 > 0.0f) && (w1 > 0.0f) && (w2 > 0.0f);
    float d2 = fminf(fminf(edge_d2q(px,py,E0,F0), edge_d2q(px,py,E1,F1)),
                     edge_d2q(px,py,E2,F2));
    float wc0 = clamp01(w0), wc1 = clamp01(w1), wc2 = clamp01(w2);
    float s = wc0 + wc1 + wc2 + 1e-12f;
    float tz = wc0*A.w + wc1*Bq.w + wc2*E0.w;
    float zp = s * frcp(tz);
    bool valid = (zp > NEARP) && (zp < FARP);
    float zn = (FARP - zp) * (1.0f/(FARP - NEARP));
    bool covered = valid && (inside || (d2 < THRESH));
    r.znm = covered ? zn : -1.0f;
    float x = d2 * INV_SIGMA;
    float e = __expf(inside ? -x : x);
    float D = frcp(1.0f + e);
    if (!inside && d2 >= THRESH) D = 0.0f;
    r.D = D;
    r.coef = valid ? D : 0.0f;
    r.s = s; r.wc0 = wc0; r.wc1 = wc1; r.wc2 = wc2;
    return r;
}

// K0: per-face constants (quads 0..10) + quad 11 = int4 bbox
// (row_lo, row_hi, quadcol_lo, quadcol_hi), dilated by RDIL.
__global__ __launch_bounds__(256) void k0_pre(const float* __restrict__ fv,
                                              const float* __restrict__ ft,
                                              float4* __restrict__ fc)
{
    const int f = blockIdx.x*256 + threadIdx.x;
    if (f >= BNB*NFACE) return;
    const float* v = fv + (size_t)f*9;
    const float* t = ft + (size_t)f*9;
    float x0=v[0],y0=v[1],z0=v[2],x1=v[3],y1=v[4],z1=v[5],x2=v[6],y2=v[7],z2=v[8];

    float a0 = y1 - y2, a1 = x2 - x1;
    float det = a0*(x0 - x2) + a1*(y0 - y2);
    det = (fabsf(det) < 1e-10f) ? 1e-10f : det;
    float rdet = 1.0f/det;
    float b0 = y2 - y0, b1 = x0 - x2;

    float4* o = fc + (size_t)f*NQ;
    o[0] = make_float4(a0*rdet, a1*rdet, -(a0*x2 + a1*y2)*rdet, 1.0f/z0);
    o[1] = make_float4(b0*rdet, b1*rdet, -(b0*x2 + b1*y2)*rdet, 1.0f/z1);

    float rz2 = 1.0f/z2;
    const float axs[3] = {x0, x1, x2}, ays[3] = {y0, y1, y2};
    const float bxs[3] = {x1, x2, x0}, bys[3] = {y1, y2, y0};
    #pragma unroll
    for (int e = 0; e < 3; ++e) {
        float ex = bxs[e] - axs[e], ey = bys[e] - ays[e];
        float inv = 1.0f/(ex*ex + ey*ey + 1e-12f);
        o[2 + 2*e] = make_float4(ex*inv, ey*inv, -(axs[e]*ex + ays[e]*ey)*inv,
                                 (e == 0) ? rz2 : 0.0f);
        o[3 + 2*e] = make_float4(axs[e], ays[e], ex, ey);
    }
    o[8]  = make_float4(t[0], t[3], t[6], 0.0f);
    o[9]  = make_float4(t[1], t[4], t[7], 0.0f);
    o[10] = make_float4(t[2], t[5], t[8], 0.0f);

    float xmn = fminf(fminf(x0,x1),x2) - RDIL, xmx = fmaxf(fmaxf(x0,x1),x2) + RDIL;
    float ymn = fminf(fminf(y0,y1),y2) - RDIL, ymx = fmaxf(fmaxf(y0,y1),y2) + RDIL;
    int jl = (int)ceilf (32.0f*xmn + 31.5f);
    int jh = (int)floorf(32.0f*xmx + 31.5f);
    int il = (int)ceilf (31.5f - 32.0f*ymx);
    int ih = (int)floorf(31.5f - 32.0f*ymn);
    jl = max(jl, 0); jh = min(jh, 63); il = max(il, 0); ih = min(ih, 63);
    int4 bb; bb.x = il; bb.y = ih; bb.z = jl >> 2; bb.w = jh >> 2;
    ((int4*)(o + 11))[0] = bb;
}

// K_bin: one wave per (tile,b) builds ordered face list (ballot compaction).
__global__ __launch_bounds__(64) void k_bin(const float4* __restrict__ fc,
                                            int* __restrict__ lists,
                                            int* __restrict__ lens)
{
    const int t = blockIdx.x, b = blockIdx.y, lane = threadIdx.x;
    const int ty0 = (t>>2)*16, ty1 = ty0+15;
    const int tx0 = (t&3)*16,  tx1 = tx0+15;
    int* lst = lists + (b*NTILE + t)*NFACE;
    int base = 0;
    for (int r = 0; r < NFACE/64; ++r) {
        int f = r*64 + lane;
        int4 bb = ((const int4*)fc)[(size_t)(b*NFACE+f)*NQ + 11];
        bool hit = (bb.y >= ty0) && (bb.x <= ty1) &&
                   (bb.w*4 + 3 >= tx0) && (bb.z*4 <= tx1);
        unsigned long long m = __ballot(hit);
        if (hit) {
            int pos = __popcll(m & ((1ull << lane) - 1ull));
            lst[base + pos] = f;
        }
        base += __popcll(m);
    }
    if (lane == 0) lens[b*NTILE + t] = base;
}

// kA: per (tile,b) block: full softmax over the tile's face list.
// Writes images + per-pixel m and invd.
__global__ __launch_bounds__(256) void kA(const float4* __restrict__ fc,
                                          const int* __restrict__ lists,
                                          const int* __restrict__ lens,
                                          float* __restrict__ imgs,
                                          float* __restrict__ m_arr,
                                          float* __restrict__ invd_arr)
{
    __shared__ float4 sfc[CHB*NQ];     // 12288 B
    const int t = blockIdx.x, b = blockIdx.y, tid = threadIdx.x;
    const int len = lens[b*NTILE + t];
    const int* lst = lists + (b*NTILE + t)*NFACE;

    const int rr = tid >> 4, cc = tid & 15;
    const int i = (t>>2)*16 + rr;
    const int j = (t&3)*16 + cc;
    const int jq = j >> 2;
    const float px = (2.0f*(float)j + 1.0f - (float)ISZ) * (1.0f/(float)ISZ);
    const float py = ((float)ISZ - 1.0f - 2.0f*(float)i) * (1.0f/(float)ISZ);

    // pass A: per-pixel max of znm over all listed faces
    float m = EPSV;
    for (int base = 0; base < len; base += CHB) {
        const int n = min(CHB, len - base);
        __syncthreads();
        for (int e = tid; e < n*NQ; e += 256) {
            int k = (int)((unsigned)e / (unsigned)NQ);
            int qd = e - k*NQ;
            sfc[e] = fc[((size_t)b*NFACE + lst[base + k])*NQ + qd];
        }
        __syncthreads();
        for (int k = 0; k < n; ++k) {
            const float4* cf = &sfc[k*NQ];
            int4 bb = ((const int4*)cf)[11];
            bool act = (i >= bb.x) && (i <= bb.y) && (jq >= bb.z) && (jq <= bb.w);
            if (act) {
                Ev r = face_pixel(cf, px, py);
                m = fmaxf(m, r.znm);
            }
        }
    }

    // pass B: denom, rgb numerators, alpha product
    float denom = __expf((EPSV - m) * INV_GAMMA);   // wbg
    float rgb0 = 0.f, rgb1 = 0.f, rgb2 = 0.f, pr = 1.f;
    for (int base = 0; base < len; base += CHB) {
        const int n = min(CHB, len - base);
        __syncthreads();
        for (int e = tid; e < n*NQ; e += 256) {
            int k = (int)((unsigned)e / (unsigned)NQ);
            int qd = e - k*NQ;
            sfc[e] = fc[((size_t)b*NFACE + lst[base + k])*NQ + qd];
        }
        __syncthreads();
        for (int k = 0; k < n; ++k) {
            const float4* cf = &sfc[k*NQ];
            int4 bb = ((const int4*)cf)[11];
            bool act = (i >= bb.x) && (i <= bb.y) && (jq >= bb.z) && (jq <= bb.w);
            if (act) {
                Ev r = face_pixel(cf, px, py);
                float wt = r.coef * __expf((r.znm - m) * INV_GAMMA);
                float wrs = wt * frcp(r.s);
                float4 X0 = cf[8], X1 = cf[9], X2 = cf[10];
                denom += wt;
                rgb0 += wrs * (r.wc0*X0.x + r.wc1*X0.y + r.wc2*X0.z);
                rgb1 += wrs * (r.wc0*X1.x + r.wc1*X1.y + r.wc2*X1.z);
                rgb2 += wrs * (r.wc0*X2.x + r.wc1*X2.y + r.wc2*X2.z);
                pr   *= (1.0f - r.D);
            }
        }
    }
    float invd = frcp(denom);

    const int pix = i*64 + j;
    m_arr[b*NPIX + pix]    = m;
    invd_arr[b*NPIX + pix] = invd;
    size_t ip = (size_t)b*4*NPIX + pix;
    imgs[ip]          = rgb0 * invd;   // BG = 0
    imgs[ip +   NPIX] = rgb1 * invd;
    imgs[ip + 2*NPIX] = rgb2 * invd;
    imgs[ip + 3*NPIX] = 1.0f - pr;
}

// kB: one thread per 4-pixel quad; 4 blocks per face (16 rows each).
// Outside the face's bbox -> exact zeros; inside -> final D and aggr.
__global__ __launch_bounds__(256) void kB(const float4* __restrict__ fc,
                                          const float* __restrict__ m_arr,
                                          const float* __restrict__ invd_arr,
                                          float* __restrict__ outD,
                                          float* __restrict__ outW)
{
    const int bid = blockIdx.x;            // < BNB*NFACE*4
    const int tid = threadIdx.x;
    const int fg   = bid >> 2;             // global face index
    const int part = bid & 3;
    const int b    = fg >> 10;
    const int i    = part*16 + (tid >> 4);
    const int q    = tid & 15;

    const int4 bb = ((const int4*)fc)[(size_t)fg*NQ + 11];
    const size_t off = (size_t)fg*NPIX + i*64 + q*4;

    float4 Dq = make_float4(0.f,0.f,0.f,0.f);
    float4 Wq = make_float4(0.f,0.f,0.f,0.f);

    const bool act = (i >= bb.x) && (i <= bb.y) && (q >= bb.z) && (q <= bb.w);
    if (act) {
        const float4* cf = fc + (size_t)fg*NQ;
        const int pixb = i*64 + q*4;
        const float4 m4  = *(const float4*)(m_arr   + b*NPIX + pixb);
        const float4 iv4 = *(const float4*)(invd_arr + b*NPIX + pixb);
        const float py = ((float)ISZ - 1.0f - 2.0f*(float)i) * (1.0f/(float)ISZ);
        float D[4], W[4];
        #pragma unroll
        for (int l = 0; l < 4; ++l) {
            const int jj = q*4 + l;
            const float px = (2.0f*(float)jj + 1.0f - (float)ISZ) * (1.0f/(float)ISZ);
            Ev r = face_pixel(cf, px, py);
            const float mm = (l==0)?m4.x:(l==1)?m4.y:(l==2)?m4.z:m4.w;
            const float iv = (l==0)?iv4.x:(l==1)?iv4.y:(l==2)?iv4.z:iv4.w;
            D[l] = r.D;
            W[l] = r.coef * __expf((r.znm - mm) * INV_GAMMA) * iv;
        }
        Dq = make_float4(D[0],D[1],D[2],D[3]);
        Wq = make_float4(W[0],W[1],W[2],W[3]);
    }
    *(float4*)(outD + off) = Dq;
    *(float4*)(outW + off) = Wq;
}

extern "C" void kernel_launch(void* const* d_in, const int* in_sizes, int n_in,
                              void* d_out, int out_size, void* d_ws, size_t ws_size,
                              hipStream_t stream) {
    const float* fv = (const float*)d_in[0];
    const float* ft = (const float*)d_in[1];
    float* out  = (float*)d_out;
    float* imgs = out;
    float* outD = out + (size_t)BNB*4*NPIX;
    float* outA = outD + (size_t)BNB*NFACE*NPIX;

    float* ws     = (float*)d_ws;
    float4* fcq   = (float4*)ws;                          // 768 KB
    int*   lists  = (int*)(ws + (size_t)BNB*NFACE*NQ*4);  // 256 KB
    int*   lens   = lists + BNB*NTILE*NFACE;              // 64 ints
    float* m_arr  = (float*)(lens + BNB*NTILE);           // 64 KB
    float* invd_a = m_arr + BNB*NPIX;                     // 64 KB

    k0_pre<<<(BNB*NFACE + 255)/256, 256, 0, stream>>>(fv, ft, fcq);
    k_bin<<<dim3(NTILE, BNB), 64, 0, stream>>>(fcq, lists, lens);
    kA<<<dim3(NTILE, BNB), 256, 0, stream>>>(fcq, lists, lens, imgs, m_arr, invd_a);
    kB<<<BNB*NFACE*4, 256, 0, stream>>>(fcq, m_arr, invd_a, outD, outA);
}

// Round 5
// 46.818 us; speedup vs baseline: 3.1846x; 2.0217x over previous
//
#include <hip/hip_runtime.h>
#include <math.h>

#define ISZ   64
#define NPIX  4096
#define BNB   4
#define NFACE 1024
#define NT8   64            // 8x8 grid of 8x8-px tiles
#define CHB   64            // faces staged per LDS chunk in kA2
#define NEARP 1.0f
#define FARP  100.0f
#define EPSV  0.001f
#define INV_SIGMA 1.0e5f
#define INV_GAMMA 1.0e4f
#define THRESH 9.210240366975849e-5f  // SIGMA*log(1/DIST_EPS - 1)
#define RDIL  0.0105f                 // > sqrt(THRESH)=0.009597, fp margin
#define NQ    12                      // 11 const quads + 1 bbox int4

__device__ __forceinline__ float frcp(float x){ return __builtin_amdgcn_rcpf(x); }
__device__ __forceinline__ float clamp01(float x){ return fminf(fmaxf(x, 0.0f), 1.0f); }

__device__ __forceinline__ float edge_d2q(float px, float py, float4 E, float4 F){
    float tt = clamp01(E.x*px + E.y*py + E.z);
    float dx = px - F.x - tt*F.z;
    float dy = py - F.y - tt*F.w;
    return dx*dx + dy*dy;
}

struct Ev { float znm, D, coef, s, wc0, wc1, wc2; };
__device__ __forceinline__ Ev face_pixel(const float4* __restrict__ cf,
                                         float px, float py)
{
    Ev r;
    float4 A = cf[0], Bq = cf[1], E0 = cf[2], F0 = cf[3];
    float4 E1 = cf[4], F1 = cf[5], E2 = cf[6], F2 = cf[7];
    float w0 = A.x*px + A.y*py + A.z;
    float w1 = Bq.x*px + Bq.y*py + Bq.z;
    float w2 = 1.0f - w0 - w1;
    bool inside = (w0 > 0.0f) && (w1 > 0.0f) && (w2 > 0.0f);
    float d2 = fminf(fminf(edge_d2q(px,py,E0,F0), edge_d2q(px,py,E1,F1)),
                     edge_d2q(px,py,E2,F2));
    float wc0 = clamp01(w0), wc1 = clamp01(w1), wc2 = clamp01(w2);
    float s = wc0 + wc1 + wc2 + 1e-12f;
    float tz = wc0*A.w + wc1*Bq.w + wc2*E0.w;
    float zp = s * frcp(tz);
    bool valid = (zp > NEARP) && (zp < FARP);
    float zn = (FARP - zp) * (1.0f/(FARP - NEARP));
    bool covered = valid && (inside || (d2 < THRESH));
    r.znm = covered ? zn : -1.0f;
    float x = d2 * INV_SIGMA;
    float e = __expf(inside ? -x : x);
    float D = frcp(1.0f + e);
    if (!inside && d2 >= THRESH) D = 0.0f;
    r.D = D;
    r.coef = valid ? D : 0.0f;
    r.s = s; r.wc0 = wc0; r.wc1 = wc1; r.wc2 = wc2;
    return r;
}

// K0: per-face constants (quads 0..10) + quad 11 = int4 bbox
// (row_lo, row_hi, quadcol_lo, quadcol_hi), dilated by RDIL.
__global__ __launch_bounds__(256) void k0_pre(const float* __restrict__ fv,
                                              const float* __restrict__ ft,
                                              float4* __restrict__ fc)
{
    const int f = blockIdx.x*256 + threadIdx.x;
    if (f >= BNB*NFACE) return;
    const float* v = fv + (size_t)f*9;
    const float* t = ft + (size_t)f*9;
    float x0=v[0],y0=v[1],z0=v[2],x1=v[3],y1=v[4],z1=v[5],x2=v[6],y2=v[7],z2=v[8];

    float a0 = y1 - y2, a1 = x2 - x1;
    float det = a0*(x0 - x2) + a1*(y0 - y2);
    det = (fabsf(det) < 1e-10f) ? 1e-10f : det;
    float rdet = 1.0f/det;
    float b0 = y2 - y0, b1 = x0 - x2;

    float4* o = fc + (size_t)f*NQ;
    o[0] = make_float4(a0*rdet, a1*rdet, -(a0*x2 + a1*y2)*rdet, 1.0f/z0);
    o[1] = make_float4(b0*rdet, b1*rdet, -(b0*x2 + b1*y2)*rdet, 1.0f/z1);

    float rz2 = 1.0f/z2;
    const float axs[3] = {x0, x1, x2}, ays[3] = {y0, y1, y2};
    const float bxs[3] = {x1, x2, x0}, bys[3] = {y1, y2, y0};
    #pragma unroll
    for (int e = 0; e < 3; ++e) {
        float ex = bxs[e] - axs[e], ey = bys[e] - ays[e];
        float inv = 1.0f/(ex*ex + ey*ey + 1e-12f);
        o[2 + 2*e] = make_float4(ex*inv, ey*inv, -(axs[e]*ex + ays[e]*ey)*inv,
                                 (e == 0) ? rz2 : 0.0f);
        o[3 + 2*e] = make_float4(axs[e], ays[e], ex, ey);
    }
    o[8]  = make_float4(t[0], t[3], t[6], 0.0f);
    o[9]  = make_float4(t[1], t[4], t[7], 0.0f);
    o[10] = make_float4(t[2], t[5], t[8], 0.0f);

    float xmn = fminf(fminf(x0,x1),x2) - RDIL, xmx = fmaxf(fmaxf(x0,x1),x2) + RDIL;
    float ymn = fminf(fminf(y0,y1),y2) - RDIL, ymx = fmaxf(fmaxf(y0,y1),y2) + RDIL;
    int jl = (int)ceilf (32.0f*xmn + 31.5f);
    int jh = (int)floorf(32.0f*xmx + 31.5f);
    int il = (int)ceilf (31.5f - 32.0f*ymx);
    int ih = (int)floorf(31.5f - 32.0f*ymn);
    jl = max(jl, 0); jh = min(jh, 63); il = max(il, 0); ih = min(ih, 63);
    int4 bb; bb.x = il; bb.y = ih; bb.z = jl >> 2; bb.w = jh >> 2;
    ((int4*)(o + 11))[0] = bb;
}

// K_bin: one wave per (8x8 tile, b) builds ordered face list.
__global__ __launch_bounds__(64) void k_bin(const float4* __restrict__ fc,
                                            int* __restrict__ lists,
                                            int* __restrict__ lens)
{
    const int t = blockIdx.x, b = blockIdx.y, lane = threadIdx.x;
    const int ty0 = (t>>3)*8, ty1 = ty0+7;
    const int tx0 = (t&7)*8,  tx1 = tx0+7;
    int* lst = lists + (b*NT8 + t)*NFACE;
    int base = 0;
    for (int r = 0; r < NFACE/64; ++r) {
        int f = r*64 + lane;
        int4 bb = ((const int4*)fc)[(size_t)(b*NFACE+f)*NQ + 11];
        bool hit = (bb.y >= ty0) && (bb.x <= ty1) &&
                   (bb.w*4 + 3 >= tx0) && (bb.z*4 <= tx1);
        unsigned long long m = __ballot(hit);
        if (hit) {
            int pos = __popcll(m & ((1ull << lane) - 1ull));
            lst[base + pos] = f;
        }
        base += __popcll(m);
    }
    if (lane == 0) lens[b*NT8 + t] = base;
}

// kA2: per (8x8 tile, b): online softmax over the tile's face list.
// 256 threads = 64 pixels x 4 list-slices; LDS merge; writes images, m, invd.
__global__ __launch_bounds__(256) void kA2(const float4* __restrict__ fc,
                                           const int* __restrict__ lists,
                                           const int* __restrict__ lens,
                                           float* __restrict__ imgs,
                                           float* __restrict__ m_arr,
                                           float* __restrict__ invd_arr)
{
    __shared__ float4 sfc[CHB*NQ];                  // 12 KiB
    __shared__ float lm[256], lsum[256], lr0[256], lr1[256], lr2[256], lpr[256];
    const int t = blockIdx.x, b = blockIdx.y, tid = threadIdx.x;
    const int len = lens[b*NT8 + t];
    const int* lst = lists + (b*NT8 + t)*NFACE;

    const int p  = tid & 63;           // pixel within tile
    const int q  = tid >> 6;           // list slice 0..3
    const int i  = (t>>3)*8 + (p>>3);
    const int j  = (t&7)*8  + (p&7);
    const int jq = j >> 2;
    const float px = (2.0f*(float)j + 1.0f - (float)ISZ) * (1.0f/(float)ISZ);
    const float py = ((float)ISZ - 1.0f - 2.0f*(float)i) * (1.0f/(float)ISZ);

    float pm = EPSV, ps = 0.f, p0 = 0.f, p1 = 0.f, p2 = 0.f, ppr = 1.f;

    for (int base = 0; base < len; base += CHB) {
        const int n = min(CHB, len - base);
        __syncthreads();
        for (int e = tid; e < n*NQ; e += 256) {
            int k = (int)((unsigned)e / (unsigned)NQ);
            int qd = e - k*NQ;
            sfc[e] = fc[((size_t)b*NFACE + lst[base + k])*NQ + qd];
        }
        __syncthreads();
        for (int k = q; k < n; k += 4) {
            const float4* cf = &sfc[k*NQ];
            int4 bb = ((const int4*)cf)[11];
            bool act = (i >= bb.x) && (i <= bb.y) && (jq >= bb.z) && (jq <= bb.w);
            if (act) {
                Ev r = face_pixel(cf, px, py);
                float wt;
                if (r.znm > pm) {                       // new running max
                    float sc = __expf((pm - r.znm) * INV_GAMMA);
                    ps *= sc; p0 *= sc; p1 *= sc; p2 *= sc;
                    pm = r.znm;
                    wt = r.coef;
                } else {
                    wt = r.coef * __expf((r.znm - pm) * INV_GAMMA);
                }
                float wrs = wt * frcp(r.s);
                float4 X0 = cf[8], X1 = cf[9], X2 = cf[10];
                ps += wt;
                p0 += wrs * (r.wc0*X0.x + r.wc1*X0.y + r.wc2*X0.z);
                p1 += wrs * (r.wc0*X1.x + r.wc1*X1.y + r.wc2*X1.z);
                p2 += wrs * (r.wc0*X2.x + r.wc1*X2.y + r.wc2*X2.z);
                ppr *= (1.0f - r.D);
            }
        }
    }

    lm[tid] = pm; lsum[tid] = ps; lr0[tid] = p0; lr1[tid] = p1; lr2[tid] = p2;
    lpr[tid] = ppr;
    __syncthreads();

    if (tid < 64) {
        float m = EPSV;
        #pragma unroll
        for (int s = 0; s < 4; ++s) m = fmaxf(m, lm[s*64 + tid]);
        float denom = __expf((EPSV - m) * INV_GAMMA);   // wbg
        float r0 = 0.f, r1 = 0.f, r2 = 0.f, pr = 1.f;
        #pragma unroll
        for (int s = 0; s < 4; ++s) {
            const int o = s*64 + tid;
            float e = __expf((lm[o] - m) * INV_GAMMA);
            denom += lsum[o] * e;
            r0 += lr0[o] * e;
            r1 += lr1[o] * e;
            r2 += lr2[o] * e;
            pr *= lpr[o];
        }
        float invd = frcp(denom);
        const int ii = (t>>3)*8 + (tid>>3);
        const int jj = (t&7)*8  + (tid&7);
        const int pix = ii*64 + jj;
        m_arr[b*NPIX + pix]    = m;
        invd_arr[b*NPIX + pix] = invd;
        size_t ip = (size_t)b*4*NPIX + pix;
        imgs[ip]          = r0 * invd;   // BG = 0
        imgs[ip +   NPIX] = r1 * invd;
        imgs[ip + 2*NPIX] = r2 * invd;
        imgs[ip + 3*NPIX] = 1.0f - pr;
    }
}

// kB: one thread per 4-pixel quad; 4 blocks per face (16 rows each).
// Outside the face's bbox -> exact zeros; inside -> final D and aggr.
__global__ __launch_bounds__(256) void kB(const float4* __restrict__ fc,
                                          const float* __restrict__ m_arr,
                                          const float* __restrict__ invd_arr,
                                          float* __restrict__ outD,
                                          float* __restrict__ outW)
{
    const int bid = blockIdx.x;            // < BNB*NFACE*4
    const int tid = threadIdx.x;
    const int fg   = bid >> 2;             // global face index
    const int part = bid & 3;
    const int b    = fg >> 10;
    const int i    = part*16 + (tid >> 4);
    const int q    = tid & 15;

    const int4 bb = ((const int4*)fc)[(size_t)fg*NQ + 11];
    const size_t off = (size_t)fg*NPIX + i*64 + q*4;

    float4 Dq = make_float4(0.f,0.f,0.f,0.f);
    float4 Wq = make_float4(0.f,0.f,0.f,0.f);

    const bool act = (i >= bb.x) && (i <= bb.y) && (q >= bb.z) && (q <= bb.w);
    if (act) {
        const float4* cf = fc + (size_t)fg*NQ;
        const int pixb = i*64 + q*4;
        const float4 m4  = *(const float4*)(m_arr    + b*NPIX + pixb);
        const float4 iv4 = *(const float4*)(invd_arr + b*NPIX + pixb);
        const float py = ((float)ISZ - 1.0f - 2.0f*(float)i) * (1.0f/(float)ISZ);
        float D[4], W[4];
        #pragma unroll
        for (int l = 0; l < 4; ++l) {
            const int jj = q*4 + l;
            const float px = (2.0f*(float)jj + 1.0f - (float)ISZ) * (1.0f/(float)ISZ);
            Ev r = face_pixel(cf, px, py);
            const float mm = (l==0)?m4.x:(l==1)?m4.y:(l==2)?m4.z:m4.w;
            const float iv = (l==0)?iv4.x:(l==1)?iv4.y:(l==2)?iv4.z:iv4.w;
            D[l] = r.D;
            W[l] = r.coef * __expf((r.znm - mm) * INV_GAMMA) * iv;
        }
        Dq = make_float4(D[0],D[1],D[2],D[3]);
        Wq = make_float4(W[0],W[1],W[2],W[3]);
    }
    *(float4*)(outD + off) = Dq;
    *(float4*)(outW + off) = Wq;
}

extern "C" void kernel_launch(void* const* d_in, const int* in_sizes, int n_in,
                              void* d_out, int out_size, void* d_ws, size_t ws_size,
                              hipStream_t stream) {
    const float* fv = (const float*)d_in[0];
    const float* ft = (const float*)d_in[1];
    float* out  = (float*)d_out;
    float* imgs = out;
    float* outD = out + (size_t)BNB*4*NPIX;
    float* outA = outD + (size_t)BNB*NFACE*NPIX;

    float* ws     = (float*)d_ws;
    float4* fcq   = (float4*)ws;                          // 768 KB
    int*   lists  = (int*)(ws + (size_t)BNB*NFACE*NQ*4);  // 4*64*1024 ints = 1 MB
    int*   lens   = lists + BNB*NT8*NFACE;                // 256 ints
    float* m_arr  = (float*)(lens + BNB*NT8);             // 64 KB
    float* invd_a = m_arr + BNB*NPIX;                     // 64 KB

    k0_pre<<<(BNB*NFACE + 255)/256, 256, 0, stream>>>(fv, ft, fcq);
    k_bin<<<dim3(NT8, BNB), 64, 0, stream>>>(fcq, lists, lens);
    kA2<<<dim3(NT8, BNB), 256, 0, stream>>>(fcq, lists, lens, imgs, m_arr, invd_a);
    kB<<<BNB*NFACE*4, 256, 0, stream>>>(fcq, m_arr, invd_a, outD, outA);
}

// Round 6
// 45.173 us; speedup vs baseline: 3.3006x; 1.0364x over previous
//
#include <hip/hip_runtime.h>
#include <math.h>

#define ISZ   64
#define NPIX  4096
#define BNB   4
#define NFACE 1024
#define NT8   64            // 8x8 grid of 8x8-px tiles
#define NEARP 1.0f
#define FARP  100.0f
#define EPSV  0.001f
#define INV_SIGMA 1.0e5f
#define INV_GAMMA 1.0e4f
#define THRESH 9.210240366975849e-5f  // SIGMA*log(1/DIST_EPS - 1)
#define RDIL  0.0105f                 // > sqrt(THRESH)=0.009597, fp margin
#define NQ    12                      // 11 const quads + 1 bbox int4

__device__ __forceinline__ float frcp(float x){ return __builtin_amdgcn_rcpf(x); }
__device__ __forceinline__ float clamp01(float x){ return fminf(fmaxf(x, 0.0f), 1.0f); }

__device__ __forceinline__ float edge_d2q(float px, float py, float4 E, float4 F){
    float tt = clamp01(E.x*px + E.y*py + E.z);
    float dx = px - F.x - tt*F.z;
    float dy = py - F.y - tt*F.w;
    return dx*dx + dy*dy;
}

struct Ev { float znm, D, coef, s, wc0, wc1, wc2; };
__device__ __forceinline__ Ev face_pixel(const float4* __restrict__ cf,
                                         float px, float py)
{
    Ev r;
    float4 A = cf[0], Bq = cf[1], E0 = cf[2], F0 = cf[3];
    float4 E1 = cf[4], F1 = cf[5], E2 = cf[6], F2 = cf[7];
    float w0 = A.x*px + A.y*py + A.z;
    float w1 = Bq.x*px + Bq.y*py + Bq.z;
    float w2 = 1.0f - w0 - w1;
    bool inside = (w0 > 0.0f) && (w1 > 0.0f) && (w2 > 0.0f);
    float d2 = fminf(fminf(edge_d2q(px,py,E0,F0), edge_d2q(px,py,E1,F1)),
                     edge_d2q(px,py,E2,F2));
    float wc0 = clamp01(w0), wc1 = clamp01(w1), wc2 = clamp01(w2);
    float s = wc0 + wc1 + wc2 + 1e-12f;
    float tz = wc0*A.w + wc1*Bq.w + wc2*E0.w;
    float zp = s * frcp(tz);
    bool valid = (zp > NEARP) && (zp < FARP);
    float zn = (FARP - zp) * (1.0f/(FARP - NEARP));
    bool covered = valid && (inside || (d2 < THRESH));
    r.znm = covered ? zn : -1.0f;
    float x = d2 * INV_SIGMA;
    float e = __expf(inside ? -x : x);
    float D = frcp(1.0f + e);
    if (!inside && d2 >= THRESH) D = 0.0f;
    r.D = D;
    r.coef = valid ? D : 0.0f;
    r.s = s; r.wc0 = wc0; r.wc1 = wc1; r.wc2 = wc2;
    return r;
}

// Dilated integer bbox (row_lo,row_hi,quadcol_lo,quadcol_hi). Identical float
// ops everywhere -> identical result -> fill/compute sets are exact complements.
__device__ __forceinline__ int4 face_bbox(const float* __restrict__ v){
    float x0=v[0], y0=v[1], x1=v[3], y1=v[4], x2=v[6], y2=v[7];
    float xmn = fminf(fminf(x0,x1),x2) - RDIL, xmx = fmaxf(fmaxf(x0,x1),x2) + RDIL;
    float ymn = fminf(fminf(y0,y1),y2) - RDIL, ymx = fmaxf(fmaxf(y0,y1),y2) + RDIL;
    int jl = (int)ceilf (32.0f*xmn + 31.5f);
    int jh = (int)floorf(32.0f*xmx + 31.5f);
    int il = (int)ceilf (31.5f - 32.0f*ymx);
    int ih = (int)floorf(31.5f - 32.0f*ymn);
    jl = max(jl, 0); jh = min(jh, 63); il = max(il, 0); ih = min(ih, 63);
    int4 bb; bb.x = il; bb.y = ih; bb.z = jl >> 2; bb.w = jh >> 2;
    return bb;
}

// Per-face constants: quads 0..10 + bbox int4 in quad 11.
__device__ __forceinline__ void face_consts(const float* __restrict__ v,
                                            const float* __restrict__ t,
                                            float4* __restrict__ o){
    float x0=v[0],y0=v[1],z0=v[2],x1=v[3],y1=v[4],z1=v[5],x2=v[6],y2=v[7],z2=v[8];
    float a0 = y1 - y2, a1 = x2 - x1;
    float det = a0*(x0 - x2) + a1*(y0 - y2);
    det = (fabsf(det) < 1e-10f) ? 1e-10f : det;
    float rdet = 1.0f/det;
    float b0 = y2 - y0, b1 = x0 - x2;
    o[0] = make_float4(a0*rdet, a1*rdet, -(a0*x2 + a1*y2)*rdet, 1.0f/z0);
    o[1] = make_float4(b0*rdet, b1*rdet, -(b0*x2 + b1*y2)*rdet, 1.0f/z1);
    float rz2 = 1.0f/z2;
    const float axs[3] = {x0, x1, x2}, ays[3] = {y0, y1, y2};
    const float bxs[3] = {x1, x2, x0}, bys[3] = {y1, y2, y0};
    #pragma unroll
    for (int e = 0; e < 3; ++e) {
        float ex = bxs[e] - axs[e], ey = bys[e] - ays[e];
        float inv = 1.0f/(ex*ex + ey*ey + 1e-12f);
        o[2 + 2*e] = make_float4(ex*inv, ey*inv, -(axs[e]*ex + ays[e]*ey)*inv,
                                 (e == 0) ? rz2 : 0.0f);
        o[3 + 2*e] = make_float4(axs[e], ays[e], ex, ey);
    }
    o[8]  = make_float4(t[0], t[3], t[6], 0.0f);
    o[9]  = make_float4(t[1], t[4], t[7], 0.0f);
    o[10] = make_float4(t[2], t[5], t[8], 0.0f);
    int4 bb = face_bbox(v);
    ((int4*)(o + 11))[0] = bb;
}

// K1: role-split. Blocks [0,256): per-(8x8 tile,b) online softmax (inline
// binning + constants). Blocks [256, 256+16384): zero-fill all non-bbox quads.
__global__ __launch_bounds__(256) void k_fused(const float* __restrict__ fv,
                                               const float* __restrict__ ft,
                                               float* __restrict__ imgs,
                                               float* __restrict__ m_arr,
                                               float* __restrict__ invd_arr,
                                               float* __restrict__ outD,
                                               float* __restrict__ outW)
{
    const int bid = blockIdx.x, tid = threadIdx.x;

    if (bid >= BNB*NT8) {
        // ---- fill role: one quarter-face per block, bbox is wave-uniform ----
        const int rb = bid - BNB*NT8;
        const int fg = rb >> 2, part = rb & 3;
        const int i = part*16 + (tid >> 4), q = tid & 15;
        const int4 bb = face_bbox(fv + (size_t)fg*9);
        const bool hole = (i >= bb.x) && (i <= bb.y) && (q >= bb.z) && (q <= bb.w);
        if (!hole) {
            size_t off = (size_t)fg*NPIX + i*64 + q*4;
            float4 z = make_float4(0.f,0.f,0.f,0.f);
            *(float4*)(outD + off) = z;
            *(float4*)(outW + off) = z;
        }
        return;
    }

    // ---- softmax role ----
    __shared__ float4 sfc[64*NQ];                   // 12 KiB
    __shared__ int   sfid[64];
    __shared__ int   snh;
    __shared__ float lm[256], lsum[256], lr0[256], lr1[256], lr2[256], lpr[256];

    const int t = bid & (NT8-1), b = bid >> 6;
    const int ty0 = (t>>3)*8, ty1 = ty0+7;
    const int tx0 = (t&7)*8,  tx1 = tx0+7;

    const int p  = tid & 63;           // pixel within tile
    const int qs = tid >> 6;           // list slice 0..3
    const int i  = ty0 + (p>>3);
    const int j  = tx0 + (p&7);
    const int jq = j >> 2;
    const float px = (2.0f*(float)j + 1.0f - (float)ISZ) * (1.0f/(float)ISZ);
    const float py = ((float)ISZ - 1.0f - 2.0f*(float)i) * (1.0f/(float)ISZ);

    float pm = EPSV, ps = 0.f, p0 = 0.f, p1 = 0.f, p2 = 0.f, ppr = 1.f;

    for (int c0 = 0; c0 < NFACE; c0 += 64) {
        __syncthreads();
        if (tid < 64) {
            const int f = c0 + tid;
            int4 bb = face_bbox(fv + (size_t)(b*NFACE + f)*9);
            bool hit = (bb.x <= bb.y) && (bb.z <= bb.w) &&
                       (bb.y >= ty0) && (bb.x <= ty1) &&
                       (bb.w*4 + 3 >= tx0) && (bb.z*4 <= tx1);
            unsigned long long mb = __ballot(hit);
            if (hit) {
                int pos = __popcll(mb & ((1ull << tid) - 1ull));
                sfid[pos] = f;
            }
            if (tid == 0) snh = __popcll(mb);
        }
        __syncthreads();
        const int nh = snh;
        if (tid < nh) {
            const int f = sfid[tid];
            face_consts(fv + (size_t)(b*NFACE + f)*9,
                        ft + (size_t)(b*NFACE + f)*9, &sfc[tid*NQ]);
        }
        __syncthreads();
        for (int k = qs; k < nh; k += 4) {
            const float4* cf = &sfc[k*NQ];
            int4 bb = ((const int4*)cf)[11];
            bool act = (i >= bb.x) && (i <= bb.y) && (jq >= bb.z) && (jq <= bb.w);
            if (act) {
                Ev r = face_pixel(cf, px, py);
                float wt;
                if (r.znm > pm) {
                    float sc = __expf((pm - r.znm) * INV_GAMMA);
                    ps *= sc; p0 *= sc; p1 *= sc; p2 *= sc;
                    pm = r.znm;
                    wt = r.coef;
                } else {
                    wt = r.coef * __expf((r.znm - pm) * INV_GAMMA);
                }
                float wrs = wt * frcp(r.s);
                float4 X0 = cf[8], X1 = cf[9], X2 = cf[10];
                ps += wt;
                p0 += wrs * (r.wc0*X0.x + r.wc1*X0.y + r.wc2*X0.z);
                p1 += wrs * (r.wc0*X1.x + r.wc1*X1.y + r.wc2*X1.z);
                p2 += wrs * (r.wc0*X2.x + r.wc1*X2.y + r.wc2*X2.z);
                ppr *= (1.0f - r.D);
            }
        }
    }

    lm[tid] = pm; lsum[tid] = ps; lr0[tid] = p0; lr1[tid] = p1; lr2[tid] = p2;
    lpr[tid] = ppr;
    __syncthreads();

    if (tid < 64) {
        float m = EPSV;
        #pragma unroll
        for (int s = 0; s < 4; ++s) m = fmaxf(m, lm[s*64 + tid]);
        float denom = __expf((EPSV - m) * INV_GAMMA);   // wbg
        float r0 = 0.f, r1 = 0.f, r2 = 0.f, pr = 1.f;
        #pragma unroll
        for (int s = 0; s < 4; ++s) {
            const int o = s*64 + tid;
            float e = __expf((lm[o] - m) * INV_GAMMA);
            denom += lsum[o] * e;
            r0 += lr0[o] * e;
            r1 += lr1[o] * e;
            r2 += lr2[o] * e;
            pr *= lpr[o];
        }
        float invd = frcp(denom);
        const int ii = ty0 + (tid>>3);
        const int jj = tx0 + (tid&7);
        const int pix = ii*64 + jj;
        m_arr[b*NPIX + pix]    = m;
        invd_arr[b*NPIX + pix] = invd;
        size_t ip = (size_t)b*4*NPIX + pix;
        imgs[ip]          = r0 * invd;   // BG = 0
        imgs[ip +   NPIX] = r1 * invd;
        imgs[ip + 2*NPIX] = r2 * invd;
        imgs[ip + 3*NPIX] = 1.0f - pr;
    }
}

// K2: per-face active-quad writer — exact complement of the fill role.
__global__ __launch_bounds__(64) void kC(const float* __restrict__ fv,
                                         const float* __restrict__ ft,
                                         const float* __restrict__ m_arr,
                                         const float* __restrict__ invd_arr,
                                         float* __restrict__ outD,
                                         float* __restrict__ outW)
{
    const int fg = blockIdx.x;             // global face 0..4095
    const int b  = fg >> 10;
    const float* v = fv + (size_t)fg*9;
    const int4 bb = face_bbox(v);
    const int nrow = bb.y - bb.x + 1, nq = bb.w - bb.z + 1;
    if (nrow <= 0 || nq <= 0) return;

    float4 cf[NQ];
    face_consts(v, ft + (size_t)fg*9, cf);

    const int area = nrow * nq;
    for (int a = threadIdx.x; a < area; a += 64) {
        const int r = a / nq;
        const int c = a - r*nq;
        const int i = bb.x + r, q = bb.z + c;
        const int pixb = i*64 + q*4;
        const float4 m4  = *(const float4*)(m_arr    + b*NPIX + pixb);
        const float4 iv4 = *(const float4*)(invd_arr + b*NPIX + pixb);
        const float py = ((float)ISZ - 1.0f - 2.0f*(float)i) * (1.0f/(float)ISZ);
        float D[4], W[4];
        #pragma unroll
        for (int l = 0; l < 4; ++l) {
            const int jj = q*4 + l;
            const float px = (2.0f*(float)jj + 1.0f - (float)ISZ) * (1.0f/(float)ISZ);
            Ev r2 = face_pixel(cf, px, py);
            const float mm = (l==0)?m4.x:(l==1)?m4.y:(l==2)?m4.z:m4.w;
            const float iv = (l==0)?iv4.x:(l==1)?iv4.y:(l==2)?iv4.z:iv4.w;
            D[l] = r2.D;
            W[l] = r2.coef * __expf((r2.znm - mm) * INV_GAMMA) * iv;
        }
        const size_t off = (size_t)fg*NPIX + pixb;
        *(float4*)(outD + off) = make_float4(D[0],D[1],D[2],D[3]);
        *(float4*)(outW + off) = make_float4(W[0],W[1],W[2],W[3]);
    }
}

extern "C" void kernel_launch(void* const* d_in, const int* in_sizes, int n_in,
                              void* d_out, int out_size, void* d_ws, size_t ws_size,
                              hipStream_t stream) {
    const float* fv = (const float*)d_in[0];
    const float* ft = (const float*)d_in[1];
    float* out  = (float*)d_out;
    float* imgs = out;
    float* outD = out + (size_t)BNB*4*NPIX;
    float* outA = outD + (size_t)BNB*NFACE*NPIX;

    float* ws     = (float*)d_ws;
    float* m_arr  = ws;                 // 64 KB
    float* invd_a = ws + BNB*NPIX;      // 64 KB

    const int nSoft = BNB*NT8;                 // 256
    const int nFill = BNB*NFACE*4;             // 16384
    k_fused<<<nSoft + nFill, 256, 0, stream>>>(fv, ft, imgs, m_arr, invd_a,
                                               outD, outA);
    kC<<<BNB*NFACE, 64, 0, stream>>>(fv, ft, m_arr, invd_a, outD, outA);
}